// Round 1
// baseline (321.662 us; speedup 1.0000x reference)
//
#include <hip/hip_runtime.h>

// Correlation layer: out[b, di*21+dj, i, j] = sum_c x1[b,c,i+di-10,j+dj-10] * x2[b,c,i,j]
// (zero-padded x1). B=4, C=128, W=H=128, window 21x21.
//
// Strategy (round 0, fp32 baseline):
//  - 1 block = 1 wave (64 threads), owns (b, di, 2 output rows i0..i0+1).
//  - LDS stages x1 padded rows for a chunk of KC=8 channels: [KC][2][148] floats.
//  - thread t: r = t>>5 (row), g = t&31 (pixel group of 4 consecutive cols).
//    Holds acc[21][4] in VGPRs; per channel: 1 float4 x2 load (global, coalesced),
//    6x ds_read_b128 window loads (24 floats), 84 FMAs. x2 reused 21x from regs,
//    each x1 window float feeds ~3.5 FMAs.
//  - Zero-fill LDS once per block -> padding columns/rows stay zero; staging only
//    writes in-bounds data as 8B-aligned float2 pairs (16B dst is misaligned by
//    the +10 pad, 8B is fine). Window reads stay 16B-aligned (index = 4g+4q).

#define NB 4
#define NC 128
#define NW 128
#define NH 128
#define DW 21
#define PADW 10
#define RPB 2
#define KC 8
#define NCOL 148  // NH + 2*PADW

__global__ __launch_bounds__(64) void corr_kernel(const float* __restrict__ x1,
                                                  const float* __restrict__ x2,
                                                  float* __restrict__ out) {
    __shared__ float lds[KC][RPB][NCOL];

    const int t = threadIdx.x;
    const int blk = blockIdx.x;
    const int i0blk = blk % (NW / RPB);          // 64 row-pair slots
    const int di = (blk / (NW / RPB)) % DW;      // 21 vertical displacements
    const int b = blk / ((NW / RPB) * DW);       // 4 batches
    const int i0 = i0blk * RPB;

    const int r = t >> 5;      // 0..1: which output row
    const int g = t & 31;      // pixel group
    const int j0 = g * 4;      // first of 4 consecutive output cols

    // zero-fill LDS (covers pad cols + out-of-range x1 rows for the whole kernel)
    #pragma unroll
    for (int l = 0; l < (KC * RPB * NCOL) / 64; ++l)
        ((float*)lds)[t + l * 64] = 0.0f;

    float acc[DW][4];
    #pragma unroll
    for (int dj = 0; dj < DW; ++dj)
        #pragma unroll
        for (int p = 0; p < 4; ++p) acc[dj][p] = 0.0f;

    for (int cc = 0; cc < NC; cc += KC) {
        __syncthreads();  // protect zero-fill (iter 0) / previous reads
        // stage KC channels x RPB rows x 128 cols: 512 float4s, 8 per thread
        #pragma unroll
        for (int l = 0; l < (KC * RPB * (NH / 4)) / 64; ++l) {
            const int idx = t + l * 64;       // [0,512)
            const int k = idx >> 6;           // channel within chunk
            const int rem = idx & 63;
            const int rr = rem >> 5;          // row within pair
            const int c4 = (rem & 31) * 4;    // source column (multiple of 4)
            const int arr = i0 + rr + di - PADW;  // x1 source row
            if (arr >= 0 && arr < NW) {
                const float4 v = *(const float4*)&x1[(((size_t)b * NC + cc + k) * NW + arr) * NH + c4];
                float2* dst = (float2*)&lds[k][rr][c4 + PADW];  // 8B aligned
                dst[0] = make_float2(v.x, v.y);
                dst[1] = make_float2(v.z, v.w);
            }
        }
        __syncthreads();

        #pragma unroll
        for (int k = 0; k < KC; ++k) {
            const int c = cc + k;
            const float4 xv = *(const float4*)&x2[(((size_t)b * NC + c) * NW + (i0 + r)) * NH + j0];
            float w[24];
            #pragma unroll
            for (int q = 0; q < 6; ++q) {
                const float4 wv = *(const float4*)&lds[k][r][j0 + q * 4];  // 16B aligned
                w[q * 4 + 0] = wv.x; w[q * 4 + 1] = wv.y;
                w[q * 4 + 2] = wv.z; w[q * 4 + 3] = wv.w;
            }
            const float xs[4] = {xv.x, xv.y, xv.z, xv.w};
            #pragma unroll
            for (int dj = 0; dj < DW; ++dj)
                #pragma unroll
                for (int p = 0; p < 4; ++p)
                    acc[dj][p] = fmaf(w[p + dj], xs[p], acc[dj][p]);
        }
    }

    // epilogue: 21 coalesced float4 stores per thread
    const int i = i0 + r;
    #pragma unroll
    for (int dj = 0; dj < DW; ++dj) {
        const float4 v = make_float4(acc[dj][0], acc[dj][1], acc[dj][2], acc[dj][3]);
        *(float4*)&out[(((size_t)b * (DW * DW) + di * DW + dj) * NW + i) * NH + j0] = v;
    }
}

extern "C" void kernel_launch(void* const* d_in, const int* in_sizes, int n_in,
                              void* d_out, int out_size, void* d_ws, size_t ws_size,
                              hipStream_t stream) {
    const float* x1 = (const float*)d_in[0];
    const float* x2 = (const float*)d_in[1];
    float* out = (float*)d_out;
    const int nblocks = (NW / RPB) * DW * NB;  // 64 * 21 * 4 = 5376
    corr_kernel<<<dim3(nblocks), dim3(64), 0, stream>>>(x1, x2, out);
}

// Round 2
// 280.013 us; speedup vs baseline: 1.1487x; 1.1487x over previous
//
#include <hip/hip_runtime.h>

// Correlation layer via banded bf16 MFMA GEMM.
// out[b, di*21+dj, i, j] = sum_c x1p[b,c,i+di-10,j+dj-10] * x2[b,c,i,j]
//
// Pass 1 (transpose_kernel): build channel-contiguous bf16 copies in d_ws:
//   x1T[b][r 0..147][col 0..159][c 0..127]  (r = padded row, col = padded col; zeros outside)
//   x2T[b][i][j][c 0..127]
// Pass 2 (corr_mfma): per (b,i): Y[j', j] = sum_c x1T[b][i+di][j'][c] * x2T[b][i][j][c]
//   computed as 16x16 MFMA tiles; out[dj][j] = Y[j+dj][j] (band of width 21).
//   Wave = one 16-col tile; 3 row-tiles cover j' in [j0, j0+48) ⊇ [j0, j0+36).
//   B (x2) fragments live in registers across all 21 di. Band extraction via
//   per-wave LDS patch (intra-wave only, no barriers), coalesced float4 stores.

#define NB 4
#define NC 128
#define NW 128
#define NH 128
#define DW 21
#define PAD 10
#define NROW_T 148   // NW + 2*PAD
#define NCOL_T 160   // cols padded to cover j0_max(112) + 47, 16B-friendly
#define NCH 441      // DW*DW

typedef __attribute__((ext_vector_type(8))) short short8;   // 8 bf16 = 4 VGPRs
typedef __attribute__((ext_vector_type(4))) float float4v;  // 4 fp32 acc

__device__ inline ushort f2bf(float f) {
    union { float f; uint u; } v; v.f = f;
    const uint u = v.u;
    return (ushort)((u + 0x7fffu + ((u >> 16) & 1u)) >> 16);  // RNE
}

// One block per (b, padded-x1-row r) for r<148, else (b, x2-row i=r-148).
// LDS tile[h][cp] holds channel-pair (2cp, 2cp+1) as packed bf16x2 at spatial h.
__global__ __launch_bounds__(256) void transpose_kernel(const float* __restrict__ x1,
                                                        const float* __restrict__ x2,
                                                        ushort* __restrict__ x1T,
                                                        ushort* __restrict__ x2T) {
    __shared__ uint tile[128][65];  // 65: bank-conflict-free both phases
    const int t = threadIdx.x;
    const int blk = blockIdx.x;
    const int b = blk / (NROW_T + NW);
    const int r = blk % (NROW_T + NW);

    if (r < NROW_T) {
        const int w = r - PAD;                      // source x1 row
        const bool inr = (w >= 0 && w < NW);
        if (inr) {
            #pragma unroll
            for (int it = 0; it < 32; ++it) {
                const int u = it * 256 + t;         // 8192 units: (cp, h)
                const int h = u & 127;
                const int cp = u >> 7;              // channel pair 0..63
                const float f0 = x1[(((size_t)b * NC + 2 * cp    ) * NW + w) * NH + h];
                const float f1 = x1[(((size_t)b * NC + 2 * cp + 1) * NW + w) * NH + h];
                tile[h][cp] = (uint)f2bf(f0) | ((uint)f2bf(f1) << 16);
            }
        }
        __syncthreads();
        #pragma unroll
        for (int it = 0; it < 10; ++it) {
            const int u = it * 256 + t;             // 2560 units: (col, cg)
            const int cg = u & 15;                  // group of 8 channels
            const int col = u >> 4;                 // 0..159
            uint4 v = make_uint4(0, 0, 0, 0);
            const int h = col - PAD;
            if (inr && h >= 0 && h < NH) {
                v.x = tile[h][cg * 4 + 0];
                v.y = tile[h][cg * 4 + 1];
                v.z = tile[h][cg * 4 + 2];
                v.w = tile[h][cg * 4 + 3];
            }
            *(uint4*)&x1T[(((size_t)b * NROW_T + r) * NCOL_T + col) * NC + cg * 8] = v;
        }
    } else {
        const int i = r - NROW_T;                   // x2 row
        #pragma unroll
        for (int it = 0; it < 32; ++it) {
            const int u = it * 256 + t;
            const int h = u & 127;
            const int cp = u >> 7;
            const float f0 = x2[(((size_t)b * NC + 2 * cp    ) * NW + i) * NH + h];
            const float f1 = x2[(((size_t)b * NC + 2 * cp + 1) * NW + i) * NH + h];
            tile[h][cp] = (uint)f2bf(f0) | ((uint)f2bf(f1) << 16);
        }
        __syncthreads();
        #pragma unroll
        for (int it = 0; it < 8; ++it) {
            const int u = it * 256 + t;             // 2048 units: (j, cg)
            const int cg = u & 15;
            const int j = u >> 4;                   // 0..127
            uint4 v;
            v.x = tile[j][cg * 4 + 0];
            v.y = tile[j][cg * 4 + 1];
            v.z = tile[j][cg * 4 + 2];
            v.w = tile[j][cg * 4 + 3];
            *(uint4*)&x2T[(((size_t)b * NW + i) * NH + j) * NC + cg * 8] = v;
        }
    }
}

// Block = (b, i). 8 waves, wave = col-tile j0 = wave*16.
__global__ __launch_bounds__(512) void corr_mfma(const ushort* __restrict__ x1T,
                                                 const ushort* __restrict__ x2T,
                                                 float* __restrict__ out) {
    __shared__ float yld[8][48 * 17];  // per-wave Y patch, row stride 17
    const int t = threadIdx.x;
    const int wave = t >> 6;
    const int lane = t & 63;
    const int n16 = lane & 15;   // MFMA m/n lane index
    const int q = lane >> 4;     // quad 0..3
    const int b = blockIdx.x >> 7;
    const int i = blockIdx.x & 127;
    const int j0 = wave * 16;

    // B fragments: B[k=c][n=j]; lane holds n=n16, k = q*8 + 0..7 (+32 per k-step)
    short8 Bf[4];
    const size_t base2 = (((size_t)(b * NW + i)) * NH + (j0 + n16)) * NC + q * 8;
    #pragma unroll
    for (int k4 = 0; k4 < 4; ++k4)
        Bf[k4] = *(const short8*)&x2T[base2 + k4 * 32];

    float* Y = &yld[wave][0];

    for (int di = 0; di < DW; ++di) {
        float4v acc[3] = {{0.f, 0.f, 0.f, 0.f}, {0.f, 0.f, 0.f, 0.f}, {0.f, 0.f, 0.f, 0.f}};
        const size_t base1 = ((size_t)(b * NROW_T + i + di)) * NCOL_T * NC;  // padded row i+di
        #pragma unroll
        for (int rt = 0; rt < 3; ++rt) {
            // A[m=j'][k=c]: lane m=n16, col = j0 + rt*16 + m
            const size_t ap = base1 + (size_t)(j0 + rt * 16 + n16) * NC + q * 8;
            #pragma unroll
            for (int k4 = 0; k4 < 4; ++k4) {
                const short8 Af = *(const short8*)&x1T[ap + k4 * 32];
                acc[rt] = __builtin_amdgcn_mfma_f32_16x16x32_bf16(Af, Bf[k4], acc[rt], 0, 0, 0);
            }
        }
        // C/D layout: col = n16, row(m_local) = rt*16 + q*4 + reg  -> LDS patch
        #pragma unroll
        for (int rt = 0; rt < 3; ++rt)
            #pragma unroll
            for (int reg = 0; reg < 4; ++reg)
                Y[(rt * 16 + q * 4 + reg) * 17 + n16] = acc[rt][reg];
        // band extraction: out[dj][j0+jj] = Y[jj+dj][jj]; 84 float4 units
        #pragma unroll
        for (int it = 0; it < 2; ++it) {
            const int u = it * 64 + lane;
            if (u < 84) {
                const int dj = u >> 2;
                const int jj = (u & 3) * 4;
                float4v v;
                #pragma unroll
                for (int p = 0; p < 4; ++p)
                    v[p] = Y[(jj + p + dj) * 17 + (jj + p)];
                *(float4v*)&out[(((size_t)(b * NCH + di * DW + dj)) * NW + i) * NH + j0 + jj] = v;
            }
        }
    }
}

extern "C" void kernel_launch(void* const* d_in, const int* in_sizes, int n_in,
                              void* d_out, int out_size, void* d_ws, size_t ws_size,
                              hipStream_t stream) {
    const float* x1 = (const float*)d_in[0];
    const float* x2 = (const float*)d_in[1];
    float* out = (float*)d_out;
    ushort* x1T = (ushort*)d_ws;                                   // 24,248,320 B
    ushort* x2T = x1T + (size_t)NB * NROW_T * NCOL_T * NC;         // +16,777,216 B = 41.0 MB total
    transpose_kernel<<<dim3(NB * (NROW_T + NW)), dim3(256), 0, stream>>>(x1, x2, x1T, x2T);
    corr_mfma<<<dim3(NB * NW), dim3(512), 0, stream>>>(x1T, x2T, out);
}

// Round 3
// 233.092 us; speedup vs baseline: 1.3800x; 1.2013x over previous
//
#include <hip/hip_runtime.h>

// Correlation layer via banded bf16 MFMA GEMM, LDS-staged A operand.
// out[b, di*21+dj, i, j] = sum_c x1p[b,c,i+di-10,j+dj-10] * x2[b,c,i,j]
//
// Pass 1 (transpose_kernel): bf16 channel-contiguous copies in d_ws:
//   x1T[b][r 0..147][col 0..159][c]  with 16B chunks XOR-swizzled: chunk' = cg ^ (col&15)
//   x2T[b][i][j][c]                  unswizzled (read straight to registers)
// Pass 2 (corr_mfma): block=(b,i), 8 waves (wave = 16-col j-tile).
//   Per di: DMA x1T row (i+di) -> LDS (40 KB, global_load_lds x16B), barrier,
//   each wave: 12 ds_read_b128 A-frags (swizzle-matched, ~2-way max conflicts),
//   12 mfma_f32_16x16x32_bf16, band-extract via per-wave col-major LDS patch.

#define NB 4
#define NC 128
#define NW 128
#define NH 128
#define DW 21
#define PAD 10
#define NROW_T 148   // NW + 2*PAD
#define NCOL_T 160   // padded cols; cols 148-159 are zeros
#define NCH 441      // DW*DW
#define PSTRIDE 37   // patch col stride (col-major [16][37] floats)

typedef __attribute__((ext_vector_type(8))) short short8;   // 8 bf16 = 4 VGPRs
typedef __attribute__((ext_vector_type(4))) float float4v;  // 4 fp32 acc

__device__ inline ushort f2bf(float f) {
    union { float f; uint u; } v; v.f = f;
    const uint u = v.u;
    return (ushort)((u + 0x7fffu + ((u >> 16) & 1u)) >> 16);  // RNE
}

__device__ inline void async_copy16(const void* g, void* l) {
    __builtin_amdgcn_global_load_lds(
        (const __attribute__((address_space(1))) void*)g,
        (__attribute__((address_space(3))) void*)l, 16, 0, 0);
}

// Block = (b, r): r<148 -> x1 padded row; else x2 row i = r-148.
__global__ __launch_bounds__(256) void transpose_kernel(const float* __restrict__ x1,
                                                        const float* __restrict__ x2,
                                                        ushort* __restrict__ x1T,
                                                        ushort* __restrict__ x2T) {
    __shared__ uint tile[128][65];  // [h][channel-pair], +1 pad
    const int t = threadIdx.x;
    const int blk = blockIdx.x;
    const int b = blk / (NROW_T + NW);
    const int r = blk % (NROW_T + NW);

    if (r < NROW_T) {
        const int w = r - PAD;
        const bool inr = (w >= 0 && w < NW);
        if (inr) {
            #pragma unroll
            for (int it = 0; it < 8; ++it) {
                const int u = it * 256 + t;
                const int g4 = u & 31;          // float4 group along h (coalesced)
                const int cp = u >> 5;          // channel pair 0..63
                const float4 va = *(const float4*)&x1[(((size_t)b * NC + 2 * cp    ) * NW + w) * NH + g4 * 4];
                const float4 vb = *(const float4*)&x1[(((size_t)b * NC + 2 * cp + 1) * NW + w) * NH + g4 * 4];
                tile[g4 * 4 + 0][cp] = (uint)f2bf(va.x) | ((uint)f2bf(vb.x) << 16);
                tile[g4 * 4 + 1][cp] = (uint)f2bf(va.y) | ((uint)f2bf(vb.y) << 16);
                tile[g4 * 4 + 2][cp] = (uint)f2bf(va.z) | ((uint)f2bf(vb.z) << 16);
                tile[g4 * 4 + 3][cp] = (uint)f2bf(va.w) | ((uint)f2bf(vb.w) << 16);
            }
        }
        __syncthreads();
        #pragma unroll
        for (int it = 0; it < 10; ++it) {
            const int u = it * 256 + t;
            const int cg = u & 15;              // 16B chunk (8 channels)
            const int col = u >> 4;             // 0..159
            uint4 v = make_uint4(0, 0, 0, 0);
            const int h = col - PAD;
            if (inr && h >= 0 && h < NH) {
                v.x = tile[h][cg * 4 + 0];
                v.y = tile[h][cg * 4 + 1];
                v.z = tile[h][cg * 4 + 2];
                v.w = tile[h][cg * 4 + 3];
            }
            const int chunk = cg ^ (col & 15);  // XOR swizzle for conflict-free LDS reads in pass 2
            *(uint4*)&x1T[(((size_t)b * NROW_T + r) * NCOL_T + col) * NC + chunk * 8] = v;
        }
    } else {
        const int i = r - NROW_T;
        #pragma unroll
        for (int it = 0; it < 8; ++it) {
            const int u = it * 256 + t;
            const int g4 = u & 31;
            const int cp = u >> 5;
            const float4 va = *(const float4*)&x2[(((size_t)b * NC + 2 * cp    ) * NW + i) * NH + g4 * 4];
            const float4 vb = *(const float4*)&x2[(((size_t)b * NC + 2 * cp + 1) * NW + i) * NH + g4 * 4];
            tile[g4 * 4 + 0][cp] = (uint)f2bf(va.x) | ((uint)f2bf(vb.x) << 16);
            tile[g4 * 4 + 1][cp] = (uint)f2bf(va.y) | ((uint)f2bf(vb.y) << 16);
            tile[g4 * 4 + 2][cp] = (uint)f2bf(va.z) | ((uint)f2bf(vb.z) << 16);
            tile[g4 * 4 + 3][cp] = (uint)f2bf(va.w) | ((uint)f2bf(vb.w) << 16);
        }
        __syncthreads();
        #pragma unroll
        for (int it = 0; it < 8; ++it) {
            const int u = it * 256 + t;
            const int cg = u & 15;
            const int j = u >> 4;
            uint4 v;
            v.x = tile[j][cg * 4 + 0];
            v.y = tile[j][cg * 4 + 1];
            v.z = tile[j][cg * 4 + 2];
            v.w = tile[j][cg * 4 + 3];
            *(uint4*)&x2T[(((size_t)b * NW + i) * NH + j) * NC + cg * 8] = v;  // no swizzle
        }
    }
}

// Block = (b, i). 8 waves; wave = j-tile j0 = wave*16.
__global__ __launch_bounds__(512) void corr_mfma(const ushort* __restrict__ x1T,
                                                 const ushort* __restrict__ x2T,
                                                 float* __restrict__ out) {
    __shared__ ushort abuf[NCOL_T * NC];          // 40,960 B: one x1T row (swizzled chunks)
    __shared__ float patch[8][16 * PSTRIDE];      // 18,944 B: per-wave Y patch, col-major

    const int t = threadIdx.x;
    const int wave = t >> 6;
    const int lane = t & 63;
    const int n16 = lane & 15;
    const int q = lane >> 4;
    const int b = blockIdx.x >> 7;
    const int i = blockIdx.x & 127;
    const int j0 = wave * 16;

    // B fragments (x2) once per wave: lane holds n=n16, k = q*8 + k4*32 + 0..7
    short8 Bf[4];
    const size_t base2 = (((size_t)(b * NW + i)) * NH + (j0 + n16)) * NC + q * 8;
    #pragma unroll
    for (int k4 = 0; k4 < 4; ++k4)
        Bf[k4] = *(const short8*)&x2T[base2 + k4 * 32];

    float* P = &patch[wave][0];

    for (int di = 0; di < DW; ++di) {
        __syncthreads();  // prev compute done before overwriting abuf
        // DMA x1T row (i+di): 40,960 B contiguous, 5 x 1KB per wave
        const char* rowbase = (const char*)(x1T + ((size_t)(b * NROW_T) + (i + di)) * (NCOL_T * NC));
        char* lbase = (char*)abuf;
        #pragma unroll
        for (int it = 0; it < 5; ++it) {
            const int off = wave * 5120 + it * 1024 + lane * 16;
            async_copy16(rowbase + off, lbase + off);
        }
        __syncthreads();  // vmcnt(0) drain + barrier: abuf ready

        float4v acc0 = {0.f, 0.f, 0.f, 0.f};
        float4v acc1 = {0.f, 0.f, 0.f, 0.f};
        float4v acc2 = {0.f, 0.f, 0.f, 0.f};
        const int colbase = j0 + n16;
        #pragma unroll
        for (int k4 = 0; k4 < 4; ++k4) {
            const int ch = (((q + 4 * k4) ^ n16) & 15) * 8;  // un-swizzle
            const short8 a0 = *(const short8*)&abuf[(colbase     ) * NC + ch];
            const short8 a1 = *(const short8*)&abuf[(colbase + 16) * NC + ch];
            const short8 a2 = *(const short8*)&abuf[(colbase + 32) * NC + ch];
            acc0 = __builtin_amdgcn_mfma_f32_16x16x32_bf16(a0, Bf[k4], acc0, 0, 0, 0);
            acc1 = __builtin_amdgcn_mfma_f32_16x16x32_bf16(a1, Bf[k4], acc1, 0, 0, 0);
            acc2 = __builtin_amdgcn_mfma_f32_16x16x32_bf16(a2, Bf[k4], acc2, 0, 0, 0);
        }

        // Patch (col-major, stride 37): P[col*37 + row], row = j'-j0, col = j-j0.
        // Rows needed: 0..35 (jj+p+dj <= 35). acc2 only q==0 (rows 32-35).
        #pragma unroll
        for (int reg = 0; reg < 4; ++reg) {
            P[n16 * PSTRIDE + q * 4 + reg] = acc0[reg];
            P[n16 * PSTRIDE + 16 + q * 4 + reg] = acc1[reg];
        }
        if (q == 0) {
            #pragma unroll
            for (int reg = 0; reg < 4; ++reg)
                P[n16 * PSTRIDE + 32 + reg] = acc2[reg];
        }
        // Band extraction: out[dj][j0+jj+p] = P[(jj+p)*37 + (jj+p+dj)]; conflict-free reads.
        #pragma unroll
        for (int it = 0; it < 2; ++it) {
            const int u = it * 64 + lane;
            if (u < 84) {
                const int dj = u >> 2;
                const int jj = (u & 3) * 4;
                float4v v;
                #pragma unroll
                for (int p = 0; p < 4; ++p)
                    v[p] = P[(jj + p) * (PSTRIDE + 1) + dj];
                *(float4v*)&out[(((size_t)(b * NCH + di * DW + dj)) * NW + i) * NH + j0 + jj] = v;
            }
        }
    }
}

extern "C" void kernel_launch(void* const* d_in, const int* in_sizes, int n_in,
                              void* d_out, int out_size, void* d_ws, size_t ws_size,
                              hipStream_t stream) {
    const float* x1 = (const float*)d_in[0];
    const float* x2 = (const float*)d_in[1];
    float* out = (float*)d_out;
    ushort* x1T = (ushort*)d_ws;                                   // 24,248,320 B
    ushort* x2T = x1T + (size_t)NB * NROW_T * NCOL_T * NC;         // +16,777,216 B
    transpose_kernel<<<dim3(NB * (NROW_T + NW)), dim3(256), 0, stream>>>(x1, x2, x1T, x2T);
    corr_mfma<<<dim3(NB * NW), dim3(512), 0, stream>>>(x1T, x2T, out);
}

// Round 4
// 206.656 us; speedup vs baseline: 1.5565x; 1.1279x over previous
//
#include <hip/hip_runtime.h>

// Correlation via banded bf16 MFMA GEMM, v3.
// out[b, di*21+dj, i, j] = sum_c x1p[b,c,i+di-10,j+dj-10] * x2[b,c,i,j]
//
// Pass 1 (transpose_x1): bf16 channel-contiguous x1 copy in d_ws:
//   x1T[b][r 0..147][col 0..159][c], 16B chunks XOR-swizzled chunk' = cg ^ (col&15).
//   (x2 is no longer transposed: pass 2 reads it fp32 directly for B-fragments.)
// Pass 2 (corr_mfma): block = (b, i-pair, j-half); 4 waves = 2 paired-tiles x 2 rows.
//   Rolling 2-row LDS window of 96-col x1T slices (24.6 KB each; 2x24.6+9.5 KB patch
//   = 58.6 KB, compile-safe <64 KB static; 3-buffer prefetch variant needs 73.7+ KB).
//   Wave computes 32 output cols from a 64-row A-window: 16 ds_read_b128 -> 24 MFMA
//   (6 acc tiles: rt0-2 x nt0, rt1-3 x nt1). Band extraction per nt via per-wave
//   16x37 col-major LDS patch (intra-wave, no barriers), coalesced float4 out.

#define NB 4
#define NC 128
#define NW 128
#define NH 128
#define DW 21
#define PAD 10
#define NROW_T 148   // NW + 2*PAD
#define NCOL_T 160   // padded cols (148..159 zero)
#define NCH 441
#define PS 37        // patch col stride
#define SLICE_COLS 96
#define ROW_US (NCOL_T * NC)   // ushorts per full x1T row

typedef __attribute__((ext_vector_type(8))) short short8;   // 8 bf16
typedef __attribute__((ext_vector_type(4))) float float4v;  // 4 fp32

__device__ inline ushort f2bf(float f) {
    union { float f; uint u; } v; v.f = f;
    const uint u = v.u;
    return (ushort)((u + 0x7fffu + ((u >> 16) & 1u)) >> 16);  // RNE
}

__device__ inline void async_copy16(const void* g, void* l) {
    __builtin_amdgcn_global_load_lds(
        (const __attribute__((address_space(1))) void*)g,
        (__attribute__((address_space(3))) void*)l, 16, 0, 0);
}

// One block per (b, padded row r).
__global__ __launch_bounds__(256) void transpose_x1(const float* __restrict__ x1,
                                                    ushort* __restrict__ x1T) {
    __shared__ uint tile[128][65];
    const int t = threadIdx.x;
    const int b = blockIdx.x / NROW_T;
    const int r = blockIdx.x % NROW_T;
    const int w = r - PAD;
    const bool inr = (w >= 0 && w < NW);
    if (inr) {
        #pragma unroll
        for (int it = 0; it < 8; ++it) {
            const int u = it * 256 + t;
            const int g4 = u & 31;          // float4 group along h (coalesced)
            const int cp = u >> 5;          // channel pair
            const float4 va = *(const float4*)&x1[(((size_t)b * NC + 2 * cp    ) * NW + w) * NH + g4 * 4];
            const float4 vb = *(const float4*)&x1[(((size_t)b * NC + 2 * cp + 1) * NW + w) * NH + g4 * 4];
            tile[g4 * 4 + 0][cp] = (uint)f2bf(va.x) | ((uint)f2bf(vb.x) << 16);
            tile[g4 * 4 + 1][cp] = (uint)f2bf(va.y) | ((uint)f2bf(vb.y) << 16);
            tile[g4 * 4 + 2][cp] = (uint)f2bf(va.z) | ((uint)f2bf(vb.z) << 16);
            tile[g4 * 4 + 3][cp] = (uint)f2bf(va.w) | ((uint)f2bf(vb.w) << 16);
        }
    }
    __syncthreads();
    #pragma unroll
    for (int it = 0; it < 10; ++it) {
        const int u = it * 256 + t;
        const int cg = u & 15;
        const int col = u >> 4;             // 0..159
        uint4 v = make_uint4(0, 0, 0, 0);
        const int h = col - PAD;
        if (inr && h >= 0 && h < NH) {
            v.x = tile[h][cg * 4 + 0];
            v.y = tile[h][cg * 4 + 1];
            v.z = tile[h][cg * 4 + 2];
            v.w = tile[h][cg * 4 + 3];
        }
        const int chunk = cg ^ (col & 15);  // swizzle for conflict-free pass-2 reads
        *(uint4*)&x1T[(((size_t)b * NROW_T + r) * NCOL_T + col) * NC + chunk * 8] = v;
    }
}

// Block = (b, i-pair, j-half). 256 threads = 4 waves = 2 ptiles x 2 rows.
__global__ __launch_bounds__(256) void corr_mfma(const ushort* __restrict__ x1T,
                                                 const float* __restrict__ x2,
                                                 float* __restrict__ out) {
    __shared__ ushort win[2][SLICE_COLS * NC];  // 2 x 24576 B rolling row window
    __shared__ float patch[4][16 * PS];         // 9472 B

    const int t = threadIdx.x;
    const int wave = t >> 6;
    const int lane = t & 63;
    const int n16 = lane & 15;
    const int q = lane >> 4;

    const int b = blockIdx.x >> 7;
    const int rem = blockIdx.x & 127;
    const int jhalf = rem & 1;
    const int i0 = (rem >> 1) * 2;

    const int ptile = wave >> 1;     // 0..1
    const int rowsel = wave & 1;     // 0..1
    const int i = i0 + rowsel;
    const int col0 = jhalf * 64;                 // slice base (padded col space)
    const int jbase = col0 + ptile * 32;         // wave's output-col base

    // --- B fragments straight from fp32 x2 (read once; lane n=n16, k=q*8+e+32*k4) ---
    short8 Bf[2][4];
    #pragma unroll
    for (int nt = 0; nt < 2; ++nt) {
        const int jc = jbase + nt * 16 + n16;
        #pragma unroll
        for (int k4 = 0; k4 < 4; ++k4) {
            short8 s;
            #pragma unroll
            for (int e = 0; e < 8; ++e) {
                const int c = k4 * 32 + q * 8 + e;
                s[e] = (short)f2bf(x2[(((size_t)b * NC + c) * NW + i) * NH + jc]);
            }
            Bf[nt][k4] = s;
        }
    }

    // slice pointer: row r starts at x1Ts + r*ROW_US (already offset to col0)
    const ushort* x1Ts = x1T + (size_t)b * NROW_T * ROW_US + (size_t)col0 * NC;

    // preload rows i0, i0+1
    #pragma unroll
    for (int it = 0; it < 6; ++it) {
        const int off = it * 4096 + t * 16;
        async_copy16((const char*)(x1Ts + (size_t)(i0 + 0) * ROW_US) + off, (char*)win[0] + off);
        async_copy16((const char*)(x1Ts + (size_t)(i0 + 1) * ROW_US) + off, (char*)win[1] + off);
    }
    __syncthreads();  // vmcnt(0) drain

    float* P = &patch[wave][0];
    const int lcol = ptile * 32 + n16;   // local slice col for rt=0

    for (int di = 0; di < DW; ++di) {
        const ushort* A = win[(di + rowsel) & 1];  // row i + di = i0 + rowsel + di

        float4v a00 = {0.f,0.f,0.f,0.f}, a10 = {0.f,0.f,0.f,0.f}, a20 = {0.f,0.f,0.f,0.f};
        float4v a11 = {0.f,0.f,0.f,0.f}, a21 = {0.f,0.f,0.f,0.f}, a31 = {0.f,0.f,0.f,0.f};
        #pragma unroll
        for (int k4 = 0; k4 < 4; ++k4) {
            const int ch = (((q + 4 * k4) ^ n16) & 15) * 8;  // un-swizzle (col&15 == n16)
            const short8 A0 = *(const short8*)&A[(lcol     ) * NC + ch];
            const short8 A1 = *(const short8*)&A[(lcol + 16) * NC + ch];
            const short8 A2 = *(const short8*)&A[(lcol + 32) * NC + ch];
            const short8 A3 = *(const short8*)&A[(lcol + 48) * NC + ch];
            a00 = __builtin_amdgcn_mfma_f32_16x16x32_bf16(A0, Bf[0][k4], a00, 0, 0, 0);
            a10 = __builtin_amdgcn_mfma_f32_16x16x32_bf16(A1, Bf[0][k4], a10, 0, 0, 0);
            a20 = __builtin_amdgcn_mfma_f32_16x16x32_bf16(A2, Bf[0][k4], a20, 0, 0, 0);
            a11 = __builtin_amdgcn_mfma_f32_16x16x32_bf16(A1, Bf[1][k4], a11, 0, 0, 0);
            a21 = __builtin_amdgcn_mfma_f32_16x16x32_bf16(A2, Bf[1][k4], a21, 0, 0, 0);
            a31 = __builtin_amdgcn_mfma_f32_16x16x32_bf16(A3, Bf[1][k4], a31, 0, 0, 0);
        }

        // epilogue per nt through the per-wave patch (col-major, stride 37)
        #pragma unroll
        for (int nt = 0; nt < 2; ++nt) {
            const float4v va = nt ? a11 : a00;   // rows (rel) 0..15
            const float4v vb = nt ? a21 : a10;   // rows 16..31
            const float4v vc = nt ? a31 : a20;   // rows 32..35 (q==0 regs)
            #pragma unroll
            for (int reg = 0; reg < 4; ++reg) {
                P[n16 * PS + q * 4 + reg]      = va[reg];
                P[n16 * PS + 16 + q * 4 + reg] = vb[reg];
            }
            if (q == 0) {
                #pragma unroll
                for (int reg = 0; reg < 4; ++reg)
                    P[n16 * PS + 32 + reg] = vc[reg];
            }
            #pragma unroll
            for (int it2 = 0; it2 < 2; ++it2) {
                const int u = it2 * 64 + lane;
                if (u < 84) {
                    const int dj = u >> 2;
                    const int jj = (u & 3) * 4;
                    float4v v;
                    #pragma unroll
                    for (int p = 0; p < 4; ++p)
                        v[p] = P[(jj + p) * (PS + 1) + dj];  // diag: col*37 + (col+dj)
                    *(float4v*)&out[(((size_t)(b * NCH + di * DW + dj)) * NW + i) * NH
                                    + jbase + nt * 16 + jj] = v;
                }
            }
        }

        __syncthreads();  // all waves done reading win[di&1]
        if (di <= 19) {   // stage row i0+di+2 (max 147) over the dead buffer
            const char* src = (const char*)(x1Ts + (size_t)(i0 + di + 2) * ROW_US);
            char* dst = (char*)win[di & 1];
            #pragma unroll
            for (int it = 0; it < 6; ++it) {
                const int off = it * 4096 + t * 16;
                async_copy16(src + off, dst + off);
            }
        }
        __syncthreads();  // vmcnt(0) drain: new row resident
    }
}

extern "C" void kernel_launch(void* const* d_in, const int* in_sizes, int n_in,
                              void* d_out, int out_size, void* d_ws, size_t ws_size,
                              hipStream_t stream) {
    const float* x1 = (const float*)d_in[0];
    const float* x2 = (const float*)d_in[1];
    float* out = (float*)d_out;
    ushort* x1T = (ushort*)d_ws;  // 4*148*160*128*2 = 24,248,320 B
    transpose_x1<<<dim3(NB * NROW_T), dim3(256), 0, stream>>>(x1, x1T);
    corr_mfma<<<dim3(NB * 128), dim3(256), 0, stream>>>(x1T, x2, out);
}

// Round 5
// 194.407 us; speedup vs baseline: 1.6546x; 1.0630x over previous
//
#include <hip/hip_runtime.h>

// Correlation via banded bf16 MFMA GEMM, v4 (RPB=4, rolling 4-buffer window,
// mid-iteration prefetch so DMA latency hides behind the epilogue).
// out[b, di*21+dj, i, j] = sum_c x1p[b,c,i+di-10,j+dj-10] * x2[b,c,i,j]
//
// Pass 1 (transpose_x1): bf16 channel-contiguous x1 copy in d_ws:
//   x1T[b][r 0..147][col 0..159][c], 16B chunks XOR-swizzled chunk' = cg ^ (col&15).
// Pass 2 (corr_mfma): block = (b, i-quad, j-quarter), 4 waves = 4 output rows.
//   Per wave: 32 output cols (nt=2), A-window = 52-col slice of x1T row i+di.
//   Row-tiles at UNALIGNED bases {0,16,32,36}: nt0 uses {0,16,32}, nt1 {16,32,36}
//   -> 16 ds_read_b128 feed 24 MFMA from a 52-col slice (13,312 B/row).
//   Window: 4 row buffers; at iter di waves read rows di..di+3; barrier after
//   A-reads frees buffer di&3, prefetch row di+4 lands there while the
//   epilogue (patch band-extract + stores) runs. 2nd barrier drains vmcnt.
//   LDS: 4*13312 + 4 patches*2368 = 62,720 B -> 2 blocks/CU (8 waves/CU).

#define NB 4
#define NC 128
#define NW 128
#define NH 128
#define DW 21
#define PAD 10
#define NROW_T 148   // NW + 2*PAD
#define NCOL_T 160   // padded cols (148..159 zero)
#define NCH 441
#define PS 37        // patch col stride (col-major [16 cols][37 rows])
#define SCOLS 52     // slice cols: 32 out + 20 halo
#define SUS (SCOLS * NC)        // 6656 ushorts = 13,312 B
#define ROW_US (NCOL_T * NC)    // 20480 ushorts per full x1T row

typedef __attribute__((ext_vector_type(8))) short short8;   // 8 bf16
typedef __attribute__((ext_vector_type(4))) float float4v;  // 4 fp32

__device__ inline ushort f2bf(float f) {
    union { float f; uint u; } v; v.f = f;
    const uint u = v.u;
    return (ushort)((u + 0x7fffu + ((u >> 16) & 1u)) >> 16);  // RNE
}

__device__ inline void async_copy16(const void* g, void* l) {
    __builtin_amdgcn_global_load_lds(
        (const __attribute__((address_space(1))) void*)g,
        (__attribute__((address_space(3))) void*)l, 16, 0, 0);
}

// Stage one 13,312 B row slice: 3 full 4 KB rounds + 1 KB tail (wave 0 only).
__device__ inline void stage_row(const ushort* src, ushort* dst, int t) {
    const char* s = (const char*)src;
    char* d = (char*)dst;
    #pragma unroll
    for (int it = 0; it < 3; ++it) {
        const int off = it * 4096 + t * 16;
        async_copy16(s + off, d + off);
    }
    if (t < 64) {  // wave-uniform (wave 0)
        const int off = 12288 + t * 16;
        async_copy16(s + off, d + off);
    }
}

// One block per (b, padded row r).
__global__ __launch_bounds__(256) void transpose_x1(const float* __restrict__ x1,
                                                    ushort* __restrict__ x1T) {
    __shared__ uint tile[128][65];
    const int t = threadIdx.x;
    const int b = blockIdx.x / NROW_T;
    const int r = blockIdx.x % NROW_T;
    const int w = r - PAD;
    const bool inr = (w >= 0 && w < NW);
    if (inr) {
        #pragma unroll
        for (int it = 0; it < 8; ++it) {
            const int u = it * 256 + t;
            const int g4 = u & 31;          // float4 group along h (coalesced)
            const int cp = u >> 5;          // channel pair
            const float4 va = *(const float4*)&x1[(((size_t)b * NC + 2 * cp    ) * NW + w) * NH + g4 * 4];
            const float4 vb = *(const float4*)&x1[(((size_t)b * NC + 2 * cp + 1) * NW + w) * NH + g4 * 4];
            tile[g4 * 4 + 0][cp] = (uint)f2bf(va.x) | ((uint)f2bf(vb.x) << 16);
            tile[g4 * 4 + 1][cp] = (uint)f2bf(va.y) | ((uint)f2bf(vb.y) << 16);
            tile[g4 * 4 + 2][cp] = (uint)f2bf(va.z) | ((uint)f2bf(vb.z) << 16);
            tile[g4 * 4 + 3][cp] = (uint)f2bf(va.w) | ((uint)f2bf(vb.w) << 16);
        }
    }
    __syncthreads();
    #pragma unroll
    for (int it = 0; it < 10; ++it) {
        const int u = it * 256 + t;
        const int cg = u & 15;
        const int col = u >> 4;             // 0..159
        uint4 v = make_uint4(0, 0, 0, 0);
        const int h = col - PAD;
        if (inr && h >= 0 && h < NH) {
            v.x = tile[h][cg * 4 + 0];
            v.y = tile[h][cg * 4 + 1];
            v.z = tile[h][cg * 4 + 2];
            v.w = tile[h][cg * 4 + 3];
        }
        const int chunk = cg ^ (col & 15);  // swizzle for conflict-free pass-2 reads
        *(uint4*)&x1T[(((size_t)b * NROW_T + r) * NCOL_T + col) * NC + chunk * 8] = v;
    }
}

// Block = (b, i-quad, j-quarter). 256 threads = 4 waves = 4 output rows.
__global__ __launch_bounds__(256) void corr_mfma(const ushort* __restrict__ x1T,
                                                 const float* __restrict__ x2,
                                                 float* __restrict__ out) {
    __shared__ ushort win[4][SUS];          // 53,248 B rolling row window
    __shared__ float patch[4][16 * PS];     // 9,472 B

    const int t = threadIdx.x;
    const int wave = t >> 6;                // = rowsel 0..3
    const int lane = t & 63;
    const int n16 = lane & 15;
    const int q = lane >> 4;

    const int b = blockIdx.x >> 7;
    const int rem = blockIdx.x & 127;
    const int jq = rem & 3;
    const int iq = rem >> 2;
    const int i0 = iq * 4;
    const int col0 = jq * 32;
    const int i = i0 + wave;

    const ushort* xbase = x1T + (size_t)(b * NROW_T) * ROW_US + (size_t)col0 * NC;

    // kick off preload of rows i0..i0+3 first (latency overlapped with B loads)
    #pragma unroll
    for (int r = 0; r < 4; ++r)
        stage_row(xbase + (size_t)(i0 + r) * ROW_US, win[r], t);

    // B fragments from fp32 x2 (read once per block; lane n=n16, k=q*8+e+32*k4)
    short8 Bf[2][4];
    #pragma unroll
    for (int nt = 0; nt < 2; ++nt) {
        const int jc = col0 + nt * 16 + n16;
        #pragma unroll
        for (int k4 = 0; k4 < 4; ++k4) {
            short8 s;
            #pragma unroll
            for (int e = 0; e < 8; ++e) {
                const int c = k4 * 32 + q * 8 + e;
                s[e] = (short)f2bf(x2[(((size_t)b * NC + c) * NW + i) * NH + jc]);
            }
            Bf[nt][k4] = s;
        }
    }

    __syncthreads();  // preload drained (vmcnt 0)

    float* P = &patch[wave][0];

    for (int di = 0; di < DW; ++di) {
        const ushort* A = win[(di + wave) & 3];  // wave's A-row = i0 + wave + di

        // 16 ds_read_b128 -> 24 MFMA. Tile bases {0,16,32,36}; nt0:{0,16,32}, nt1:{16,32,36}.
        float4v a00 = {0.f,0.f,0.f,0.f}, a01 = {0.f,0.f,0.f,0.f}, a02 = {0.f,0.f,0.f,0.f};
        float4v a10 = {0.f,0.f,0.f,0.f}, a11 = {0.f,0.f,0.f,0.f}, a12 = {0.f,0.f,0.f,0.f};
        #pragma unroll
        for (int k4 = 0; k4 < 4; ++k4) {
            const int kc = q + 4 * k4;
            const int c0 = (0  + n16);
            const int c1 = (16 + n16);
            const int c2 = (32 + n16);
            const int c3 = (36 + n16);
            const short8 A0 = *(const short8*)&A[c0 * NC + ((kc ^ (c0 & 15)) & 15) * 8];
            const short8 A1 = *(const short8*)&A[c1 * NC + ((kc ^ (c1 & 15)) & 15) * 8];
            const short8 A2 = *(const short8*)&A[c2 * NC + ((kc ^ (c2 & 15)) & 15) * 8];
            const short8 A3 = *(const short8*)&A[c3 * NC + ((kc ^ (c3 & 15)) & 15) * 8];
            a00 = __builtin_amdgcn_mfma_f32_16x16x32_bf16(A0, Bf[0][k4], a00, 0, 0, 0);
            a01 = __builtin_amdgcn_mfma_f32_16x16x32_bf16(A1, Bf[0][k4], a01, 0, 0, 0);
            a02 = __builtin_amdgcn_mfma_f32_16x16x32_bf16(A2, Bf[0][k4], a02, 0, 0, 0);
            a10 = __builtin_amdgcn_mfma_f32_16x16x32_bf16(A1, Bf[1][k4], a10, 0, 0, 0);
            a11 = __builtin_amdgcn_mfma_f32_16x16x32_bf16(A2, Bf[1][k4], a11, 0, 0, 0);
            a12 = __builtin_amdgcn_mfma_f32_16x16x32_bf16(A3, Bf[1][k4], a12, 0, 0, 0);
        }

        __syncthreads();  // barrier 1: all A-reads retired -> buffer di&3 is dead
        if (di < DW - 1)  // prefetch row i0+di+4 over it; latency hides behind epilogue
            stage_row(xbase + (size_t)(i0 + di + 4) * ROW_US, win[di & 3], t);

        // Epilogue: per nt, band-extract via per-wave col-major patch P[n*37 + r].
        #pragma unroll
        for (int nt = 0; nt < 2; ++nt) {
            const float4v va = nt ? a10 : a00;  // rel rows 0..15
            const float4v vb = nt ? a11 : a01;  // rel rows 16..31
            const float4v vc = nt ? a12 : a02;  // nt0: rows 32..47 (keep q==0 -> 32..35)
                                                // nt1: rows 20..35 (keep q==3 -> 32..35)
            #pragma unroll
            for (int reg = 0; reg < 4; ++reg) {
                P[n16 * PS + q * 4 + reg]      = va[reg];
                P[n16 * PS + 16 + q * 4 + reg] = vb[reg];
            }
            if (q == (nt ? 3 : 0)) {
                #pragma unroll
                for (int reg = 0; reg < 4; ++reg)
                    P[n16 * PS + 32 + reg] = vc[reg];
            }
            #pragma unroll
            for (int it2 = 0; it2 < 2; ++it2) {
                const int u = it2 * 64 + lane;
                if (u < 84) {
                    const int dj = u >> 2;
                    const int jj = (u & 3) * 4;
                    float4v v;
                    #pragma unroll
                    for (int p = 0; p < 4; ++p)
                        v[p] = P[(jj + p) * (PS + 1) + dj];  // col jj+p, row jj+p+dj
                    *(float4v*)&out[(((size_t)(b * NCH + di * DW + dj)) * NW + i) * NH
                                    + col0 + nt * 16 + jj] = v;
                }
            }
        }

        __syncthreads();  // barrier 2: prefetch drained; patch safe to reuse
    }
}

extern "C" void kernel_launch(void* const* d_in, const int* in_sizes, int n_in,
                              void* d_out, int out_size, void* d_ws, size_t ws_size,
                              hipStream_t stream) {
    const float* x1 = (const float*)d_in[0];
    const float* x2 = (const float*)d_in[1];
    float* out = (float*)d_out;
    ushort* x1T = (ushort*)d_ws;  // 4*148*160*128*2 = 24,248,320 B
    transpose_x1<<<dim3(NB * NROW_T), dim3(256), 0, stream>>>(x1, x1T);
    corr_mfma<<<dim3(NB * 32 * 4), dim3(256), 0, stream>>>(x1T, x2, out);
}

// Round 6
// 188.125 us; speedup vs baseline: 1.7098x; 1.0334x over previous
//
#include <hip/hip_runtime.h>

// Correlation via banded bf16 MFMA GEMM, v5.
// out[b, di*21+dj, i, j] = sum_c x1p[b,c,i+di-10,j+dj-10] * x2[b,c,i,j]
//
// Pass 1 (transpose_x1): bf16 channel-contiguous x1 copy in d_ws:
//   x1T[b][r 0..147][col 0..159][c], 16B chunks XOR-swizzled chunk' = cg ^ (col&15).
// Pass 2 (corr_mfma): block = (b, i-quad, j-quarter), 4 waves = 4 output rows,
//   XCD-swizzled grid (XCD k = one (b, i-half) band; x1T slice set 3.4 MB < 4 MB L2).
//   5-buffer rolling window of 52-col row slices; ONE barrier per di-iteration:
//     A-frag ds_reads (16 b128) -> prefetch row di+4 into buffer (di+4)%5
//     -> 24 MFMA -> band-extract epilogue (per-wave patch, distinct LDS array,
//     so no conservative LDS-DMA alias waits) -> __syncthreads (vmcnt drain is
//     covered by MFMA+epilogue ~1300 cyc).
//   LDS: 5*13,312 + 4*2,368 = 76,032 B -> 2 blocks/CU (8 waves/CU).

#define NB 4
#define NC 128
#define NW 128
#define NH 128
#define DW 21
#define PAD 10
#define NROW_T 148   // NW + 2*PAD
#define NCOL_T 160   // padded cols (148..159 zero)
#define NCH 441
#define PS 37        // patch col stride (col-major [16 cols][37 rows])
#define SCOLS 52     // slice cols: 32 out + 20 halo
#define SUS (SCOLS * NC)        // 6656 ushorts = 13,312 B
#define ROW_US (NCOL_T * NC)    // 20480 ushorts per full x1T row

typedef __attribute__((ext_vector_type(8))) short short8;   // 8 bf16
typedef __attribute__((ext_vector_type(4))) float float4v;  // 4 fp32

__device__ inline ushort f2bf(float f) {
    union { float f; uint u; } v; v.f = f;
    const uint u = v.u;
    return (ushort)((u + 0x7fffu + ((u >> 16) & 1u)) >> 16);  // RNE
}

__device__ inline void async_copy16(const void* g, void* l) {
    __builtin_amdgcn_global_load_lds(
        (const __attribute__((address_space(1))) void*)g,
        (__attribute__((address_space(3))) void*)l, 16, 0, 0);
}

// Stage one 13,312 B row slice: 3 full 4 KB rounds + 1 KB tail (wave 0 only).
__device__ inline void stage_row(const ushort* src, ushort* dst, int t) {
    const char* s = (const char*)src;
    char* d = (char*)dst;
    #pragma unroll
    for (int it = 0; it < 3; ++it) {
        const int off = it * 4096 + t * 16;
        async_copy16(s + off, d + off);
    }
    if (t < 64) {
        const int off = 12288 + t * 16;
        async_copy16(s + off, d + off);
    }
}

// One block per (b, padded row r).
__global__ __launch_bounds__(256) void transpose_x1(const float* __restrict__ x1,
                                                    ushort* __restrict__ x1T) {
    __shared__ uint tile[128][65];
    const int t = threadIdx.x;
    const int b = blockIdx.x / NROW_T;
    const int r = blockIdx.x % NROW_T;
    const int w = r - PAD;
    const bool inr = (w >= 0 && w < NW);
    if (inr) {
        #pragma unroll
        for (int it = 0; it < 8; ++it) {
            const int u = it * 256 + t;
            const int g4 = u & 31;          // float4 group along h (coalesced)
            const int cp = u >> 5;          // channel pair
            const float4 va = *(const float4*)&x1[(((size_t)b * NC + 2 * cp    ) * NW + w) * NH + g4 * 4];
            const float4 vb = *(const float4*)&x1[(((size_t)b * NC + 2 * cp + 1) * NW + w) * NH + g4 * 4];
            tile[g4 * 4 + 0][cp] = (uint)f2bf(va.x) | ((uint)f2bf(vb.x) << 16);
            tile[g4 * 4 + 1][cp] = (uint)f2bf(va.y) | ((uint)f2bf(vb.y) << 16);
            tile[g4 * 4 + 2][cp] = (uint)f2bf(va.z) | ((uint)f2bf(vb.z) << 16);
            tile[g4 * 4 + 3][cp] = (uint)f2bf(va.w) | ((uint)f2bf(vb.w) << 16);
        }
    }
    __syncthreads();
    #pragma unroll
    for (int it = 0; it < 10; ++it) {
        const int u = it * 256 + t;
        const int cg = u & 15;
        const int col = u >> 4;             // 0..159
        uint4 v = make_uint4(0, 0, 0, 0);
        const int h = col - PAD;
        if (inr && h >= 0 && h < NH) {
            v.x = tile[h][cg * 4 + 0];
            v.y = tile[h][cg * 4 + 1];
            v.z = tile[h][cg * 4 + 2];
            v.w = tile[h][cg * 4 + 3];
        }
        const int chunk = cg ^ (col & 15);  // swizzle for conflict-free pass-2 reads
        *(uint4*)&x1T[(((size_t)b * NROW_T + r) * NCOL_T + col) * NC + chunk * 8] = v;
    }
}

// Block = (b, i-quad, j-quarter), XCD-swizzled. 256 threads = 4 waves = 4 rows.
__global__ __launch_bounds__(256) void corr_mfma(const ushort* __restrict__ x1T,
                                                 const float* __restrict__ x2,
                                                 float* __restrict__ out) {
    __shared__ ushort win[5][SUS];          // 66,560 B rolling row window
    __shared__ float patch[4][16 * PS];     // 9,472 B

    const int t = threadIdx.x;
    const int wave = t >> 6;                // = row offset 0..3
    const int lane = t & 63;
    const int n16 = lane & 15;
    const int q = lane >> 4;

    // XCD swizzle: hw XCD = blockIdx%8 -> XCD k serves (b = k>>1, ihalf = k&1),
    // 64 slots = 16 i-quads x 4 j-quarters (x1T band ~3.4 MB, fits 4 MB L2).
    const int n = blockIdx.x;
    const int b = (n & 7) >> 1;
    const int ihalf = n & 1;
    const int slot = n >> 3;                // 0..63
    const int iq = ihalf * 16 + (slot >> 2);
    const int jq = slot & 3;
    const int i0 = iq * 4;
    const int col0 = jq * 32;
    const int i = i0 + wave;

    const ushort* xbase = x1T + (size_t)(b * NROW_T) * ROW_US + (size_t)col0 * NC;

    // preload rows i0..i0+3 into buffers 0..3 (buffer = (row - i0) % 5)
    #pragma unroll
    for (int r = 0; r < 4; ++r)
        stage_row(xbase + (size_t)(i0 + r) * ROW_US, win[r], t);

    // B fragments from fp32 x2 (read once per block; lane n=n16, k=q*8+e+32*k4)
    short8 Bf[2][4];
    #pragma unroll
    for (int nt = 0; nt < 2; ++nt) {
        const int jc = col0 + nt * 16 + n16;
        #pragma unroll
        for (int k4 = 0; k4 < 4; ++k4) {
            short8 s;
            #pragma unroll
            for (int e = 0; e < 8; ++e) {
                const int c = k4 * 32 + q * 8 + e;
                s[e] = (short)f2bf(x2[(((size_t)b * NC + c) * NW + i) * NH + jc]);
            }
            Bf[nt][k4] = s;
        }
    }

    __syncthreads();  // preload drained

    float* P = &patch[wave][0];

    for (int di = 0; di < DW; ++di) {
        const ushort* A = win[(di + wave) % 5];  // wave's A-row = i0 + wave + di

        // 16 ds_read_b128 first (tile bases {0,16,32,36})
        short8 Af[4][4];
        #pragma unroll
        for (int k4 = 0; k4 < 4; ++k4) {
            const int kc = q + 4 * k4;
            #pragma unroll
            for (int tl = 0; tl < 4; ++tl) {
                const int base = (tl < 3) ? tl * 16 : 36;
                const int c = base + n16;
                Af[tl][k4] = *(const short8*)&A[c * NC + ((kc ^ (c & 15)) & 15) * 8];
            }
        }

        // prefetch row i0+di+4 into buffer (di+4)%5; covered by MFMA + epilogue.
        if (di < DW - 1)
            stage_row(xbase + (size_t)(i0 + di + 4) * ROW_US, win[(di + 4) % 5], t);

        float4v a00 = {0.f,0.f,0.f,0.f}, a01 = {0.f,0.f,0.f,0.f}, a02 = {0.f,0.f,0.f,0.f};
        float4v a10 = {0.f,0.f,0.f,0.f}, a11 = {0.f,0.f,0.f,0.f}, a12 = {0.f,0.f,0.f,0.f};
        #pragma unroll
        for (int k4 = 0; k4 < 4; ++k4) {
            a00 = __builtin_amdgcn_mfma_f32_16x16x32_bf16(Af[0][k4], Bf[0][k4], a00, 0, 0, 0);
            a01 = __builtin_amdgcn_mfma_f32_16x16x32_bf16(Af[1][k4], Bf[0][k4], a01, 0, 0, 0);
            a02 = __builtin_amdgcn_mfma_f32_16x16x32_bf16(Af[2][k4], Bf[0][k4], a02, 0, 0, 0);
            a10 = __builtin_amdgcn_mfma_f32_16x16x32_bf16(Af[1][k4], Bf[1][k4], a10, 0, 0, 0);
            a11 = __builtin_amdgcn_mfma_f32_16x16x32_bf16(Af[2][k4], Bf[1][k4], a11, 0, 0, 0);
            a12 = __builtin_amdgcn_mfma_f32_16x16x32_bf16(Af[3][k4], Bf[1][k4], a12, 0, 0, 0);
        }

        // Epilogue: per nt, band-extract via per-wave col-major patch P[n*37 + r].
        #pragma unroll
        for (int nt = 0; nt < 2; ++nt) {
            const float4v va = nt ? a10 : a00;  // rel rows 0..15
            const float4v vb = nt ? a11 : a01;  // rel rows 16..31
            const float4v vc = nt ? a12 : a02;  // nt0 q==0 / nt1 q==3 -> rows 32..35
            #pragma unroll
            for (int reg = 0; reg < 4; ++reg) {
                P[n16 * PS + q * 4 + reg]      = va[reg];
                P[n16 * PS + 16 + q * 4 + reg] = vb[reg];
            }
            if (q == (nt ? 3 : 0)) {
                #pragma unroll
                for (int reg = 0; reg < 4; ++reg)
                    P[n16 * PS + 32 + reg] = vc[reg];
            }
            #pragma unroll
            for (int it2 = 0; it2 < 2; ++it2) {
                const int u = it2 * 64 + lane;
                if (u < 84) {
                    const int dj = u >> 2;
                    const int jj = (u & 3) * 4;
                    float4v v;
                    #pragma unroll
                    for (int p = 0; p < 4; ++p)
                        v[p] = P[(jj + p) * (PS + 1) + dj];  // col jj+p, row jj+p+dj
                    *(float4v*)&out[(((size_t)(b * NCH + di * DW + dj)) * NW + i) * NH
                                    + col0 + nt * 16 + jj] = v;
                }
            }
        }

        __syncthreads();  // single barrier: patch reuse + prefetch drain (covered)
    }
}

extern "C" void kernel_launch(void* const* d_in, const int* in_sizes, int n_in,
                              void* d_out, int out_size, void* d_ws, size_t ws_size,
                              hipStream_t stream) {
    const float* x1 = (const float*)d_in[0];
    const float* x2 = (const float*)d_in[1];
    float* out = (float*)d_out;
    ushort* x1T = (ushort*)d_ws;  // 4*148*160*128*2 = 24,248,320 B
    transpose_x1<<<dim3(NB * NROW_T), dim3(256), 0, stream>>>(x1, x1T);
    corr_mfma<<<dim3(NB * 32 * 4), dim3(256), 0, stream>>>(x1T, x2, out);
}